// Round 11
// baseline (260.900 us; speedup 1.0000x reference)
//
#include <hip/hip_runtime.h>

// ---------- types ----------
typedef __attribute__((ext_vector_type(8))) short bf16x8;   // 8 bf16 (4 VGPRs)
typedef __attribute__((ext_vector_type(4))) float f32x4;

__device__ __forceinline__ unsigned short f2bf(float f) {
    unsigned int u = __float_as_uint(f);
    unsigned int r = (u + 0x7fffu + ((u >> 16) & 1u)) >> 16;   // RNE
    return (unsigned short)r;
}

// x: (8,1024,64,64) f32; W: (1024,1049) f32; b: (1024,); out: (8,1024,64,64) f32
// M = 32768, K = 1049 -> pad 1088 (17 K-tiles of 64), N = 1024
#define KPAD 1088
#define NT   17

// ---------- kernel: W (1024,1049) f32 -> Wb[n][k] bf16, k padded to 1088 ----------
__global__ void kWb_conv(const float* __restrict__ W, unsigned short* __restrict__ Wb)
{
    const int o = blockIdx.x;
    for (int k = threadIdx.x; k < KPAD; k += 256) {
        float v = (k < 1049) ? W[(size_t)o * 1049 + k] : 0.f;
        Wb[(size_t)o * KPAD + k] = f2bf(v);
    }
}

// ---------- kernel: transpose+convert x -> xT[m][k] bf16 (k<1024 region) ----------
__global__ __launch_bounds__(256) void kT_conv(const float* __restrict__ x,
                                               unsigned short* __restrict__ xT)
{
    __shared__ unsigned short tile[64][128];
    const int bid = blockIdx.x;          // 4096 = 512 mtiles * 8 ctiles
    const int mst = bid >> 3;
    const int ct  = bid & 7;
    const int m0  = mst * 64;
    const int b   = m0 >> 12, ms0 = m0 & 4095;
    const int t   = threadIdx.x;
    const int msq = (t & 15) * 4;
    const int cg  = t >> 4;
    const int c0  = ct * 128 + cg * 8;

    const float* src = x + ((size_t)b * 1024 + c0) * 4096 + ms0 + msq;
    float4 v[8];
    #pragma unroll
    for (int j = 0; j < 8; ++j)
        v[j] = *(const float4*)(src + (size_t)j * 4096);

    #pragma unroll
    for (int p = 0; p < 4; ++p) {
        unsigned int w[4];
        #pragma unroll
        for (int q = 0; q < 4; ++q) {
            float lo = ((const float*)&v[2 * q])[p];
            float hi = ((const float*)&v[2 * q + 1])[p];
            w[q] = (unsigned int)f2bf(lo) | ((unsigned int)f2bf(hi) << 16);
        }
        const int row = msq + p;
        const int pch = cg ^ ((row >> 2) & 15);
        *(uint4*)&tile[row][pch * 8] = make_uint4(w[0], w[1], w[2], w[3]);
    }
    __syncthreads();

    #pragma unroll
    for (int q = 0; q < 4; ++q) {
        const int flat = q * 256 + t;
        const int row  = flat >> 4, ch = flat & 15;
        const int pch  = ch ^ ((row >> 2) & 15);
        uint4 val = *(const uint4*)&tile[row][pch * 8];
        *(uint4*)((char*)xT + (size_t)(m0 + row) * (KPAD * 2) + (size_t)(ct * 128 + ch * 8) * 2) = val;
    }
}

// ---------- kernel: local self-correlation partials ----------
// grid 512 = split(16) * b(8) * rowgroup(4). 256 thr: 16 rows x 16 col-strips(P=4).
// 4-deep register pipeline (A..D named sets, rule #20) + RAW s_barrier with
// lgkmcnt(0) ONLY. __syncthreads (rounds 3-10) emitted vmcnt(0), draining the
// just-issued global load every iteration (~700cy exposed HBM latency x64).
// The ds_write consuming a staged register gets an automatic COUNTED vmcnt (G7);
// loads now have ~3 iterations (~1300cy > 900cy HBM) before that wait.
// Liveness: at body(i): set (i+1)&3 = ch i+1 -> LDS write; set i&3 = ch i
// (LDS-resident since body(i-1)) -> reload ch i+4. Write target buf (i+1)&1 was
// last read at body(i-1), drained by its lgkmcnt(0)+barrier.
__global__ __launch_bounds__(256, 2) void k1a_corr(const float* __restrict__ x,
                                                   float* __restrict__ fpart)
{
    __shared__ float slab[2][20][68];
    const int bid   = blockIdx.x;
    const int split = bid & 15;
    const int b     = (bid >> 4) & 7;
    const int rg    = bid >> 7;
    const int y0    = rg * 16;
    const int t     = threadIdx.x;
    const int tc    = t & 15, tr = t >> 4;
    const int cs    = tc * 4;

    if (t < 160) {
        int buf = t / 80, rem = t % 80;
        int r = rem >> 2, cc = rem & 3;
        slab[buf][r][(cc < 2) ? cc : (64 + cc)] = 0.f;
    }

    float acc[25][4];
    #pragma unroll
    for (int s = 0; s < 25; ++s)
        #pragma unroll
        for (int p = 0; p < 4; ++p) acc[s][p] = 0.f;

    const float* xb = x + ((size_t)b * 1024 + split * 64) * 4096;

    const int r0 = t >> 4,         c40 = t & 15;
    const int y0r0 = y0 - 2 + r0;
    const int r1 = (t + 256) >> 4, c41 = t & 15;          // t<64 only
    const int y0r1 = y0 - 2 + r1;
    const bool has1 = (t < 64);

    #define K1A_LOAD(ch, VA, VB)                                                \
        {                                                                        \
            const float* s_ = xb + (size_t)(ch) * 4096;                          \
            VA = (y0r0 >= 0 && y0r0 < 64) ? *(const float4*)(s_ + y0r0 * 64 + c40 * 4) \
                                          : make_float4(0.f, 0.f, 0.f, 0.f);     \
            if (has1)                                                            \
                VB = (y0r1 >= 0 && y0r1 < 64) ? *(const float4*)(s_ + y0r1 * 64 + c41 * 4) \
                                              : make_float4(0.f, 0.f, 0.f, 0.f); \
        }
    #define K1A_WRITE(buf, VA, VB)                                               \
        {                                                                        \
            float2* d0 = (float2*)&slab[buf][r0][2 + c40 * 4];                   \
            d0[0] = make_float2(VA.x, VA.y);                                     \
            d0[1] = make_float2(VA.z, VA.w);                                     \
            if (has1) {                                                          \
                float2* d1 = (float2*)&slab[buf][r1][2 + c41 * 4];               \
                d1[0] = make_float2(VB.x, VB.y);                                 \
                d1[1] = make_float2(VB.z, VB.w);                                 \
            }                                                                    \
        }
    #define K1A_COMPUTE(buf)                                                     \
        {                                                                        \
            const float* base = &slab[buf][tr][cs];                              \
            float ctr[4], wf[8];                                                 \
            {                                                                    \
                const float4* pr = (const float4*)(base + 2 * 68);               \
                float4 a = pr[0], b4 = pr[1];                                    \
                wf[0]=a.x; wf[1]=a.y; wf[2]=a.z; wf[3]=a.w;                      \
                wf[4]=b4.x; wf[5]=b4.y; wf[6]=b4.z; wf[7]=b4.w;                  \
                ctr[0]=wf[2]; ctr[1]=wf[3]; ctr[2]=wf[4]; ctr[3]=wf[5];          \
                _Pragma("unroll")                                                \
                for (int dx = -2; dx <= 2; ++dx)                                 \
                    _Pragma("unroll")                                            \
                    for (int p = 0; p < 4; ++p)                                  \
                        acc[10 + dx + 2][p] += wf[p + 2 + dx] * ctr[p];          \
            }                                                                    \
            _Pragma("unroll")                                                    \
            for (int r = 0; r < 5; ++r) {                                        \
                if (r == 2) continue;                                            \
                const float4* pr = (const float4*)(base + r * 68);               \
                float4 a = pr[0], b4 = pr[1];                                    \
                wf[0]=a.x; wf[1]=a.y; wf[2]=a.z; wf[3]=a.w;                      \
                wf[4]=b4.x; wf[5]=b4.y; wf[6]=b4.z; wf[7]=b4.w;                  \
                _Pragma("unroll")                                                \
                for (int dx = -2; dx <= 2; ++dx)                                 \
                    _Pragma("unroll")                                            \
                    for (int p = 0; p < 4; ++p)                                  \
                        acc[r * 5 + dx + 2][p] += wf[p + 2 + dx] * ctr[p];       \
            }                                                                    \
        }
    #define K1A_BAR()                                                            \
        asm volatile("s_waitcnt lgkmcnt(0)" ::: "memory");                       \
        __builtin_amdgcn_s_barrier();

    // body(i): write ch i+1 -> buf (i+1)&1; reload set i&3 with ch i+4; compute ch i.
    #define K1A_BODY(i, RN0, RN1, RC0, RC1)                                      \
        if ((i) + 1 < 64) { K1A_WRITE(((i) + 1) & 1, RN0, RN1) }                 \
        K1A_LOAD(min((i) + 4, 63), RC0, RC1)                                     \
        K1A_COMPUTE((i) & 1)                                                     \
        K1A_BAR()

    float4 A0, A1, B0, B1, C0, C1, D0, D1;
    K1A_LOAD(0, A0, A1)
    K1A_LOAD(1, B0, B1)
    K1A_LOAD(2, C0, C1)
    K1A_LOAD(3, D0, D1)
    K1A_WRITE(0, A0, A1)          // ch0 -> buf0 (counted vmcnt(3) wait, auto)
    K1A_BAR()

    #pragma unroll 1
    for (int ii = 0; ii < 64; ii += 4) {
        K1A_BODY(ii + 0, B0, B1, A0, A1)
        K1A_BODY(ii + 1, C0, C1, B0, B1)
        K1A_BODY(ii + 2, D0, D1, C0, C1)
        K1A_BODY(ii + 3, A0, A1, D0, D1)
    }
    #undef K1A_LOAD
    #undef K1A_WRITE
    #undef K1A_COMPUTE
    #undef K1A_BAR
    #undef K1A_BODY

    const int mbase = b * 4096 + (y0 + tr) * 64 + cs;
    #pragma unroll
    for (int s = 0; s < 25; ++s) {
        *(float4*)(fpart + (size_t)(split * 25 + s) * 32768 + mbase) =
            make_float4(acc[s][0], acc[s][1], acc[s][2], acc[s][3]);
    }
}

// ---------- kernel: reduce 16 partials, L2-normalize, write bf16 into xT[m][1024..1088) ----------
__global__ void k1b_norm(const float* __restrict__ fpart, unsigned short* __restrict__ xT)
{
    const int m = blockIdx.x * 256 + threadIdx.x;
    float f[25];
    #pragma unroll
    for (int s = 0; s < 25; ++s) {
        float v = 0.f;
        #pragma unroll
        for (int sp = 0; sp < 16; ++sp)
            v += fpart[(size_t)(sp * 25 + s) * 32768 + m];
        f[s] = v;
    }
    float ss = 1e-6f;
    #pragma unroll
    for (int s = 0; s < 25; ++s) ss += f[s] * f[s];
    const float inv = 1.f / sqrtf(ss);

    unsigned int w[16];
    #pragma unroll
    for (int q = 0; q < 16; ++q) w[q] = 0u;
    #pragma unroll
    for (int s = 0; s < 25; ++s) {
        unsigned int h = f2bf(f[s] * inv);
        w[s >> 1] |= h << ((s & 1) * 16);
    }
    uint4* dst = (uint4*)((char*)xT + (size_t)m * (KPAD * 2) + 2048);
    dst[0] = make_uint4(w[0],  w[1],  w[2],  w[3]);
    dst[1] = make_uint4(w[4],  w[5],  w[6],  w[7]);
    dst[2] = make_uint4(w[8],  w[9],  w[10], w[11]);
    dst[3] = make_uint4(w[12], w[13], w[14], w[15]);
    uint4 z = make_uint4(0u, 0u, 0u, 0u);
    dst[4] = z; dst[5] = z; dst[6] = z; dst[7] = z;
}

// ---------- kernel: 256x256 8-phase GEMM, reads spread 12/4/8/0 across phases ----------
// (unchanged from rounds 9/10: ~79us by subtraction, passing)
__global__ __launch_bounds__(512, 2) void kgemm(const unsigned short* __restrict__ xT,
                                                const unsigned short* __restrict__ Wb,
                                                const float* __restrict__ bias,
                                                float* __restrict__ out)
{
    __shared__ unsigned short LA[2][256][64];   // 64KB
    __shared__ unsigned short LB[2][256][64];   // 64KB

    const int bid = blockIdx.x;                 // 512 blocks
    const int wg  = (bid & 7) * 64 + (bid >> 3);
    const int mt  = wg >> 2, nt = wg & 3;
    const int m0  = mt * 256, n0 = nt * 256;
    const int t   = threadIdx.x;
    const int l   = t & 63, w = t >> 6;
    const int lr  = l & 15, kq = l >> 4;
    const int wm  = w >> 2, wn = w & 3;

    const int sr = l >> 3;
    const int sp = (l & 7) ^ sr;
    const unsigned short* gA = xT + (size_t)(m0 + w * 8 + sr) * KPAD + sp * 8;
    const unsigned short* gB = Wb + (size_t)(n0 + w * 8 + sr) * KPAD + sp * 8;

    // half: 0 = A rows[0:128), 1 = A[128:256), 2 = B[0:128), 3 = B[128:256)
    auto STAGE = [&](int tt, int half) {
        if ((unsigned)tt >= NT) return;
        const int db = tt & 1;
        const size_t ko = (size_t)tt * 64;
        if (half < 2) {
            const unsigned short* g = gA + (size_t)(half * 128) * KPAD + ko;
            __builtin_amdgcn_global_load_lds((const void*)g,
                (void*)&LA[db][half * 128 + w * 8][0], 16, 0, 0);
            __builtin_amdgcn_global_load_lds((const void*)(g + (size_t)64 * KPAD),
                (void*)&LA[db][half * 128 + 64 + w * 8][0], 16, 0, 0);
        } else {
            const int hb = half - 2;
            const unsigned short* g = gB + (size_t)(hb * 128) * KPAD + ko;
            __builtin_amdgcn_global_load_lds((const void*)g,
                (void*)&LB[db][hb * 128 + w * 8][0], 16, 0, 0);
            __builtin_amdgcn_global_load_lds((const void*)(g + (size_t)64 * KPAD),
                (void*)&LB[db][hb * 128 + 64 + w * 8][0], 16, 0, 0);
        }
    };

    f32x4 zero = {0.f, 0.f, 0.f, 0.f};
    f32x4 acc[8][4];
    #pragma unroll
    for (int i = 0; i < 8; ++i)
        #pragma unroll
        for (int j = 0; j < 4; ++j) acc[i][j] = zero;

    bf16x8 a0[4][2], a1[4][2], b0[2][2], b1[2][2];

    #define LDA(dst, DB, ih)                                                     \
        _Pragma("unroll")                                                        \
        for (int i = 0; i < 4; ++i) {                                            \
            _Pragma("unroll")                                                    \
            for (int ks = 0; ks < 2; ++ks) {                                     \
                const int row = wm * 128 + ((ih) * 4 + i) * 16 + lr;             \
                const int slot = (ks * 4 + kq) ^ (row & 7);                      \
                dst[i][ks] = *(const bf16x8*)&LA[DB][row][slot * 8];             \
            }                                                                    \
        }
    #define LDB(dst, DB, jh)                                                     \
        _Pragma("unroll")                                                        \
        for (int j = 0; j < 2; ++j) {                                            \
            _Pragma("unroll")                                                    \
            for (int ks = 0; ks < 2; ++ks) {                                     \
                const int row = wn * 64 + ((jh) * 2 + j) * 16 + lr;              \
                const int slot = (ks * 4 + kq) ^ (row & 7);                      \
                dst[j][ks] = *(const bf16x8*)&LB[DB][row][slot * 8];             \
            }                                                                    \
        }
    #define MM(A, B, i0, j0)                                                     \
        _Pragma("unroll")                                                        \
        for (int ks = 0; ks < 2; ++ks) {                                         \
            _Pragma("unroll")                                                    \
            for (int i = 0; i < 4; ++i) {                                        \
                _Pragma("unroll")                                                \
                for (int j = 0; j < 2; ++j)                                      \
                    acc[(i0) + i][(j0) + j] = __builtin_amdgcn_mfma_f32_16x16x32_bf16( \
                        A[i][ks], B[j][ks], acc[(i0) + i][(j0) + j], 0, 0, 0);   \
            }                                                                    \
        }

    #define TILE(DB, TT)                                                         \
    {                                                                            \
        const int tti = (TT);                                                    \
        /* ph1: read a0(8)+b0(4); stage A-hi(t+1); MM(a0,b0) */                  \
        LDA(a0, DB, 0)                                                           \
        LDB(b0, DB, 0)                                                           \
        STAGE(tti + 1, 1);                                                       \
        asm volatile("s_waitcnt lgkmcnt(8)" ::: "memory");                       \
        __builtin_amdgcn_s_barrier();                                            \
        asm volatile("s_waitcnt lgkmcnt(0)" ::: "memory");                       \
        __builtin_amdgcn_sched_barrier(0);                                       \
        __builtin_amdgcn_s_setprio(1);                                           \
        MM(a0, b0, 0, 0)                                                         \
        __builtin_amdgcn_s_setprio(0);                                           \
        __builtin_amdgcn_s_barrier();                                            \
        /* ph2: read b1(4); stage B-hi(t+1); MM(a0,b1) */                        \
        LDB(b1, DB, 1)                                                           \
        STAGE(tti + 1, 3);                                                       \
        __builtin_amdgcn_s_barrier();                                            \
        asm volatile("s_waitcnt lgkmcnt(0)" ::: "memory");                       \
        __builtin_amdgcn_sched_barrier(0);                                       \
        __builtin_amdgcn_s_setprio(1);                                           \
        MM(a0, b1, 0, 2)                                                         \
        __builtin_amdgcn_s_setprio(0);                                           \
        __builtin_amdgcn_s_barrier();                                            \
        /* ph3: read a1(8); stage A-lo(t+2) [A-lo last read ph1]; MM(a1,b1) */   \
        LDA(a1, DB, 1)                                                           \
        STAGE(tti + 2, 0);                                                       \
        __builtin_amdgcn_s_barrier();                                            \
        asm volatile("s_waitcnt lgkmcnt(0)" ::: "memory");                       \
        __builtin_amdgcn_sched_barrier(0);                                       \
        __builtin_amdgcn_s_setprio(1);                                           \
        MM(a1, b1, 4, 2)                                                         \
        __builtin_amdgcn_s_setprio(0);                                           \
        __builtin_amdgcn_s_barrier();                                            \
        /* ph4: stage B-lo(t+2) [B-lo last read ph1]; MM(a1,b0); drain t+1 */    \
        STAGE(tti + 2, 2);                                                       \
        __builtin_amdgcn_s_barrier();                                            \
        __builtin_amdgcn_s_setprio(1);                                           \
        MM(a1, b0, 4, 0)                                                         \
        __builtin_amdgcn_s_setprio(0);                                           \
        if (tti + 2 < NT) {                                                      \
            asm volatile("s_waitcnt vmcnt(4)" ::: "memory");                     \
        } else {                                                                 \
            asm volatile("s_waitcnt vmcnt(0)" ::: "memory");                     \
        }                                                                        \
        __builtin_amdgcn_s_barrier();                                            \
    }

    // prologue FIFO: Alo0,Blo0,Ahi0,Bhi0,Alo1,Blo1 (12 loads); vmcnt(4)
    // drains tile 0 completely, leaves Alo1,Blo1 in flight (steady invariant).
    STAGE(0, 0); STAGE(0, 2); STAGE(0, 1); STAGE(0, 3);
    STAGE(1, 0); STAGE(1, 2);
    asm volatile("s_waitcnt vmcnt(4)" ::: "memory");
    __builtin_amdgcn_s_barrier();

    int tt = 0;
    #pragma unroll 1
    for (int it = 0; it < (NT - 1) / 2; ++it, tt += 2) {
        TILE(0, tt)
        TILE(1, tt + 1)
    }
    TILE(0, NT - 1)

    // epilogue: D col = lane&15 (n), row = (lane>>4)*4 + reg (m)
    const int bb = m0 >> 12;
    const int ms = (m0 & 4095) + wm * 128 + kq * 4;
    #pragma unroll
    for (int j = 0; j < 4; ++j) {
        const int n = n0 + wn * 64 + j * 16 + lr;
        const float bv = bias[n];
        float* ob = out + (size_t)bb * 4194304 + (size_t)n * 4096 + ms;
        #pragma unroll
        for (int i = 0; i < 8; ++i) {
            f32x4 v = acc[i][j];
            float4 o = make_float4(fmaxf(v[0] + bv, 0.f), fmaxf(v[1] + bv, 0.f),
                                   fmaxf(v[2] + bv, 0.f), fmaxf(v[3] + bv, 0.f));
            *(float4*)(ob + i * 16) = o;
        }
    }
    #undef LDA
    #undef LDB
    #undef MM
    #undef TILE
}

// ---------- launch ----------
extern "C" void kernel_launch(void* const* d_in, const int* in_sizes, int n_in,
                              void* d_out, int out_size, void* d_ws, size_t ws_size,
                              hipStream_t stream)
{
    const float* x    = (const float*)d_in[0];
    const float* W    = (const float*)d_in[1];
    const float* bias = (const float*)d_in[2];
    float* out        = (float*)d_out;

    char* ws = (char*)d_ws;
    // ws: xT 71,303,168 B ; Wb 2,228,224 B (total 73.5MB); fpart (52.4MB) in d_out
    // scratch (kgemm overwrites all of d_out afterwards -> deterministic replays).
    unsigned short* xT = (unsigned short*)ws;
    unsigned short* Wb = (unsigned short*)(ws + 71303168);
    float* fpart       = (float*)d_out;

    kWb_conv<<<1024, 256, 0, stream>>>(W, Wb);
    kT_conv <<<4096, 256, 0, stream>>>(x, xT);
    k1a_corr<<<512,  256, 0, stream>>>(x, fpart);
    k1b_norm<<<128,  256, 0, stream>>>(fpart, xT);
    kgemm   <<<512,  512, 0, stream>>>(xT, Wb, bias, out);
}

// Round 12
// 205.383 us; speedup vs baseline: 1.2703x; 1.2703x over previous
//
#include <hip/hip_runtime.h>

// ---------- types ----------
typedef __attribute__((ext_vector_type(8))) short bf16x8;   // 8 bf16 (4 VGPRs)
typedef __attribute__((ext_vector_type(4))) float f32x4;

__device__ __forceinline__ unsigned short f2bf(float f) {
    unsigned int u = __float_as_uint(f);
    unsigned int r = (u + 0x7fffu + ((u >> 16) & 1u)) >> 16;   // RNE
    return (unsigned short)r;
}

// x: (8,1024,64,64) f32; W: (1024,1049) f32; b: (1024,); out: (8,1024,64,64) f32
// M = 32768, K = 1049 -> pad 1088 (17 K-tiles of 64), N = 1024
#define KPAD 1088
#define NT   17

// ---------- kernel: W (1024,1049) f32 -> Wb[n][k] bf16, k padded to 1088 ----------
__global__ void kWb_conv(const float* __restrict__ W, unsigned short* __restrict__ Wb)
{
    const int o = blockIdx.x;
    for (int k = threadIdx.x; k < KPAD; k += 256) {
        float v = (k < 1049) ? W[(size_t)o * 1049 + k] : 0.f;
        Wb[(size_t)o * KPAD + k] = f2bf(v);
    }
}

// ---------- kernel: transpose+convert x -> xT[m][k] bf16 (k<1024 region) ----------
__global__ __launch_bounds__(256) void kT_conv(const float* __restrict__ x,
                                               unsigned short* __restrict__ xT)
{
    __shared__ unsigned short tile[64][128];
    const int bid = blockIdx.x;          // 4096 = 512 mtiles * 8 ctiles
    const int mst = bid >> 3;
    const int ct  = bid & 7;
    const int m0  = mst * 64;
    const int b   = m0 >> 12, ms0 = m0 & 4095;
    const int t   = threadIdx.x;
    const int msq = (t & 15) * 4;
    const int cg  = t >> 4;
    const int c0  = ct * 128 + cg * 8;

    const float* src = x + ((size_t)b * 1024 + c0) * 4096 + ms0 + msq;
    float4 v[8];
    #pragma unroll
    for (int j = 0; j < 8; ++j)
        v[j] = *(const float4*)(src + (size_t)j * 4096);

    #pragma unroll
    for (int p = 0; p < 4; ++p) {
        unsigned int w[4];
        #pragma unroll
        for (int q = 0; q < 4; ++q) {
            float lo = ((const float*)&v[2 * q])[p];
            float hi = ((const float*)&v[2 * q + 1])[p];
            w[q] = (unsigned int)f2bf(lo) | ((unsigned int)f2bf(hi) << 16);
        }
        const int row = msq + p;
        const int pch = cg ^ ((row >> 2) & 15);
        *(uint4*)&tile[row][pch * 8] = make_uint4(w[0], w[1], w[2], w[3]);
    }
    __syncthreads();

    #pragma unroll
    for (int q = 0; q < 4; ++q) {
        const int flat = q * 256 + t;
        const int row  = flat >> 4, ch = flat & 15;
        const int pch  = ch ^ ((row >> 2) & 15);
        uint4 val = *(const uint4*)&tile[row][pch * 8];
        *(uint4*)((char*)xT + (size_t)(m0 + row) * (KPAD * 2) + (size_t)(ct * 128 + ch * 8) * 2) = val;
    }
}

// ---------- kernel: local self-correlation partials (round-8 proven version) ----------
// grid 512 = split(16) * b(8) * rowgroup(4). 256 thr: 16 rows x 16 col-strips(P=4).
// 2-deep register staging + __syncthreads. Round-11's 4-deep variant pushed VGPR
// past the 128 occupancy step -> spill -> 2x regression; this version fits.
__global__ __launch_bounds__(256, 2) void k1a_corr(const float* __restrict__ x,
                                                   float* __restrict__ fpart)
{
    __shared__ float slab[2][20][68];
    const int bid   = blockIdx.x;
    const int split = bid & 15;
    const int b     = (bid >> 4) & 7;
    const int rg    = bid >> 7;
    const int y0    = rg * 16;
    const int t     = threadIdx.x;
    const int tc    = t & 15, tr = t >> 4;
    const int cs    = tc * 4;

    if (t < 160) {
        int buf = t / 80, rem = t % 80;
        int r = rem >> 2, cc = rem & 3;
        slab[buf][r][(cc < 2) ? cc : (64 + cc)] = 0.f;
    }

    float acc[25][4];
    #pragma unroll
    for (int s = 0; s < 25; ++s)
        #pragma unroll
        for (int p = 0; p < 4; ++p) acc[s][p] = 0.f;

    const float* xb = x + ((size_t)b * 1024 + split * 64) * 4096;

    const int r0 = t >> 4,         c40 = t & 15;
    const int y0r0 = y0 - 2 + r0;
    const int r1 = (t + 256) >> 4, c41 = t & 15;          // t<64 only
    const int y0r1 = y0 - 2 + r1;
    const bool has1 = (t < 64);

    #define K1A_LOAD(ch, VA, VB)                                                \
        {                                                                        \
            const float* s_ = xb + (size_t)(ch) * 4096;                          \
            VA = (y0r0 >= 0 && y0r0 < 64) ? *(const float4*)(s_ + y0r0 * 64 + c40 * 4) \
                                          : make_float4(0.f, 0.f, 0.f, 0.f);     \
            if (has1)                                                            \
                VB = (y0r1 >= 0 && y0r1 < 64) ? *(const float4*)(s_ + y0r1 * 64 + c41 * 4) \
                                              : make_float4(0.f, 0.f, 0.f, 0.f); \
        }
    #define K1A_WRITE(buf, VA, VB)                                               \
        {                                                                        \
            float2* d0 = (float2*)&slab[buf][r0][2 + c40 * 4];                   \
            d0[0] = make_float2(VA.x, VA.y);                                     \
            d0[1] = make_float2(VA.z, VA.w);                                     \
            if (has1) {                                                          \
                float2* d1 = (float2*)&slab[buf][r1][2 + c41 * 4];               \
                d1[0] = make_float2(VB.x, VB.y);                                 \
                d1[1] = make_float2(VB.z, VB.w);                                 \
            }                                                                    \
        }
    #define K1A_COMPUTE(buf)                                                     \
        {                                                                        \
            const float* base = &slab[buf][tr][cs];                              \
            float ctr[4], wf[8];                                                 \
            {                                                                    \
                const float4* pr = (const float4*)(base + 2 * 68);               \
                float4 a = pr[0], b4 = pr[1];                                    \
                wf[0]=a.x; wf[1]=a.y; wf[2]=a.z; wf[3]=a.w;                      \
                wf[4]=b4.x; wf[5]=b4.y; wf[6]=b4.z; wf[7]=b4.w;                  \
                ctr[0]=wf[2]; ctr[1]=wf[3]; ctr[2]=wf[4]; ctr[3]=wf[5];          \
                _Pragma("unroll")                                                \
                for (int dx = -2; dx <= 2; ++dx)                                 \
                    _Pragma("unroll")                                            \
                    for (int p = 0; p < 4; ++p)                                  \
                        acc[10 + dx + 2][p] += wf[p + 2 + dx] * ctr[p];          \
            }                                                                    \
            _Pragma("unroll")                                                    \
            for (int r = 0; r < 5; ++r) {                                        \
                if (r == 2) continue;                                            \
                const float4* pr = (const float4*)(base + r * 68);               \
                float4 a = pr[0], b4 = pr[1];                                    \
                wf[0]=a.x; wf[1]=a.y; wf[2]=a.z; wf[3]=a.w;                      \
                wf[4]=b4.x; wf[5]=b4.y; wf[6]=b4.z; wf[7]=b4.w;                  \
                _Pragma("unroll")                                                \
                for (int dx = -2; dx <= 2; ++dx)                                 \
                    _Pragma("unroll")                                            \
                    for (int p = 0; p < 4; ++p)                                  \
                        acc[r * 5 + dx + 2][p] += wf[p + 2 + dx] * ctr[p];       \
            }                                                                    \
        }

    float4 Sa0, Sa1, Sb0, Sb1;
    K1A_LOAD(0, Sa0, Sa1)
    K1A_LOAD(1, Sb0, Sb1)
    K1A_WRITE(0, Sa0, Sa1)
    K1A_LOAD(2, Sa0, Sa1)
    __syncthreads();

    for (int i = 0; i < 64; i += 2) {
        K1A_WRITE(1, Sb0, Sb1)
        K1A_LOAD(min(i + 3, 63), Sb0, Sb1)
        K1A_COMPUTE(0)
        __syncthreads();
        K1A_WRITE(0, Sa0, Sa1)
        K1A_LOAD(min(i + 4, 63), Sa0, Sa1)
        K1A_COMPUTE(1)
        __syncthreads();
    }
    #undef K1A_LOAD
    #undef K1A_WRITE
    #undef K1A_COMPUTE

    const int mbase = b * 4096 + (y0 + tr) * 64 + cs;
    #pragma unroll
    for (int s = 0; s < 25; ++s) {
        *(float4*)(fpart + (size_t)(split * 25 + s) * 32768 + mbase) =
            make_float4(acc[s][0], acc[s][1], acc[s][2], acc[s][3]);
    }
}

// ---------- kernel: reduce 16 partials, L2-normalize, write bf16 into xT[m][1024..1088) ----------
__global__ void k1b_norm(const float* __restrict__ fpart, unsigned short* __restrict__ xT)
{
    const int m = blockIdx.x * 256 + threadIdx.x;
    float f[25];
    #pragma unroll
    for (int s = 0; s < 25; ++s) {
        float v = 0.f;
        #pragma unroll
        for (int sp = 0; sp < 16; ++sp)
            v += fpart[(size_t)(sp * 25 + s) * 32768 + m];
        f[s] = v;
    }
    float ss = 1e-6f;
    #pragma unroll
    for (int s = 0; s < 25; ++s) ss += f[s] * f[s];
    const float inv = 1.f / sqrtf(ss);

    unsigned int w[16];
    #pragma unroll
    for (int q = 0; q < 16; ++q) w[q] = 0u;
    #pragma unroll
    for (int s = 0; s < 25; ++s) {
        unsigned int h = f2bf(f[s] * inv);
        w[s >> 1] |= h << ((s & 1) * 16);
    }
    uint4* dst = (uint4*)((char*)xT + (size_t)m * (KPAD * 2) + 2048);
    dst[0] = make_uint4(w[0],  w[1],  w[2],  w[3]);
    dst[1] = make_uint4(w[4],  w[5],  w[6],  w[7]);
    dst[2] = make_uint4(w[8],  w[9],  w[10], w[11]);
    dst[3] = make_uint4(w[12], w[13], w[14], w[15]);
    uint4 z = make_uint4(0u, 0u, 0u, 0u);
    dst[4] = z; dst[5] = z; dst[6] = z; dst[7] = z;
}

// ---------- kernel: 256x256 8-phase GEMM, reads spread 12/4/8/0 across phases ----------
// (unchanged from rounds 9-11: ~79us by subtraction, ~924 TF, passing)
__global__ __launch_bounds__(512, 2) void kgemm(const unsigned short* __restrict__ xT,
                                                const unsigned short* __restrict__ Wb,
                                                const float* __restrict__ bias,
                                                float* __restrict__ out)
{
    __shared__ unsigned short LA[2][256][64];   // 64KB
    __shared__ unsigned short LB[2][256][64];   // 64KB

    const int bid = blockIdx.x;                 // 512 blocks
    const int wg  = (bid & 7) * 64 + (bid >> 3);
    const int mt  = wg >> 2, nt = wg & 3;
    const int m0  = mt * 256, n0 = nt * 256;
    const int t   = threadIdx.x;
    const int l   = t & 63, w = t >> 6;
    const int lr  = l & 15, kq = l >> 4;
    const int wm  = w >> 2, wn = w & 3;

    const int sr = l >> 3;
    const int sp = (l & 7) ^ sr;
    const unsigned short* gA = xT + (size_t)(m0 + w * 8 + sr) * KPAD + sp * 8;
    const unsigned short* gB = Wb + (size_t)(n0 + w * 8 + sr) * KPAD + sp * 8;

    // half: 0 = A rows[0:128), 1 = A[128:256), 2 = B[0:128), 3 = B[128:256)
    auto STAGE = [&](int tt, int half) {
        if ((unsigned)tt >= NT) return;
        const int db = tt & 1;
        const size_t ko = (size_t)tt * 64;
        if (half < 2) {
            const unsigned short* g = gA + (size_t)(half * 128) * KPAD + ko;
            __builtin_amdgcn_global_load_lds((const void*)g,
                (void*)&LA[db][half * 128 + w * 8][0], 16, 0, 0);
            __builtin_amdgcn_global_load_lds((const void*)(g + (size_t)64 * KPAD),
                (void*)&LA[db][half * 128 + 64 + w * 8][0], 16, 0, 0);
        } else {
            const int hb = half - 2;
            const unsigned short* g = gB + (size_t)(hb * 128) * KPAD + ko;
            __builtin_amdgcn_global_load_lds((const void*)g,
                (void*)&LB[db][hb * 128 + w * 8][0], 16, 0, 0);
            __builtin_amdgcn_global_load_lds((const void*)(g + (size_t)64 * KPAD),
                (void*)&LB[db][hb * 128 + 64 + w * 8][0], 16, 0, 0);
        }
    };

    f32x4 zero = {0.f, 0.f, 0.f, 0.f};
    f32x4 acc[8][4];
    #pragma unroll
    for (int i = 0; i < 8; ++i)
        #pragma unroll
        for (int j = 0; j < 4; ++j) acc[i][j] = zero;

    bf16x8 a0[4][2], a1[4][2], b0[2][2], b1[2][2];

    #define LDA(dst, DB, ih)                                                     \
        _Pragma("unroll")                                                        \
        for (int i = 0; i < 4; ++i) {                                            \
            _Pragma("unroll")                                                    \
            for (int ks = 0; ks < 2; ++ks) {                                     \
                const int row = wm * 128 + ((ih) * 4 + i) * 16 + lr;             \
                const int slot = (ks * 4 + kq) ^ (row & 7);                      \
                dst[i][ks] = *(const bf16x8*)&LA[DB][row][slot * 8];             \
            }                                                                    \
        }
    #define LDB(dst, DB, jh)                                                     \
        _Pragma("unroll")                                                        \
        for (int j = 0; j < 2; ++j) {                                            \
            _Pragma("unroll")                                                    \
            for (int ks = 0; ks < 2; ++ks) {                                     \
                const int row = wn * 64 + ((jh) * 2 + j) * 16 + lr;              \
                const int slot = (ks * 4 + kq) ^ (row & 7);                      \
                dst[j][ks] = *(const bf16x8*)&LB[DB][row][slot * 8];             \
            }                                                                    \
        }
    #define MM(A, B, i0, j0)                                                     \
        _Pragma("unroll")                                                        \
        for (int ks = 0; ks < 2; ++ks) {                                         \
            _Pragma("unroll")                                                    \
            for (int i = 0; i < 4; ++i) {                                        \
                _Pragma("unroll")                                                \
                for (int j = 0; j < 2; ++j)                                      \
                    acc[(i0) + i][(j0) + j] = __builtin_amdgcn_mfma_f32_16x16x32_bf16( \
                        A[i][ks], B[j][ks], acc[(i0) + i][(j0) + j], 0, 0, 0);   \
            }                                                                    \
        }

    #define TILE(DB, TT)                                                         \
    {                                                                            \
        const int tti = (TT);                                                    \
        /* ph1: read a0(8)+b0(4); stage A-hi(t+1); MM(a0,b0) */                  \
        LDA(a0, DB, 0)                                                           \
        LDB(b0, DB, 0)                                                           \
        STAGE(tti + 1, 1);                                                       \
        asm volatile("s_waitcnt lgkmcnt(8)" ::: "memory");                       \
        __builtin_amdgcn_s_barrier();                                            \
        asm volatile("s_waitcnt lgkmcnt(0)" ::: "memory");                       \
        __builtin_amdgcn_sched_barrier(0);                                       \
        __builtin_amdgcn_s_setprio(1);                                           \
        MM(a0, b0, 0, 0)                                                         \
        __builtin_amdgcn_s_setprio(0);                                           \
        __builtin_amdgcn_s_barrier();                                            \
        /* ph2: read b1(4); stage B-hi(t+1); MM(a0,b1) */                        \
        LDB(b1, DB, 1)                                                           \
        STAGE(tti + 1, 3);                                                       \
        __builtin_amdgcn_s_barrier();                                            \
        asm volatile("s_waitcnt lgkmcnt(0)" ::: "memory");                       \
        __builtin_amdgcn_sched_barrier(0);                                       \
        __builtin_amdgcn_s_setprio(1);                                           \
        MM(a0, b1, 0, 2)                                                         \
        __builtin_amdgcn_s_setprio(0);                                           \
        __builtin_amdgcn_s_barrier();                                            \
        /* ph3: read a1(8); stage A-lo(t+2) [A-lo last read ph1]; MM(a1,b1) */   \
        LDA(a1, DB, 1)                                                           \
        STAGE(tti + 2, 0);                                                       \
        __builtin_amdgcn_s_barrier();                                            \
        asm volatile("s_waitcnt lgkmcnt(0)" ::: "memory");                       \
        __builtin_amdgcn_sched_barrier(0);                                       \
        __builtin_amdgcn_s_setprio(1);                                           \
        MM(a1, b1, 4, 2)                                                         \
        __builtin_amdgcn_s_setprio(0);                                           \
        __builtin_amdgcn_s_barrier();                                            \
        /* ph4: stage B-lo(t+2) [B-lo last read ph1]; MM(a1,b0); drain t+1 */    \
        STAGE(tti + 2, 2);                                                       \
        __builtin_amdgcn_s_barrier();                                            \
        __builtin_amdgcn_s_setprio(1);                                           \
        MM(a1, b0, 4, 0)                                                         \
        __builtin_amdgcn_s_setprio(0);                                           \
        if (tti + 2 < NT) {                                                      \
            asm volatile("s_waitcnt vmcnt(4)" ::: "memory");                     \
        } else {                                                                 \
            asm volatile("s_waitcnt vmcnt(0)" ::: "memory");                     \
        }                                                                        \
        __builtin_amdgcn_s_barrier();                                            \
    }

    // prologue FIFO: Alo0,Blo0,Ahi0,Bhi0,Alo1,Blo1 (12 loads); vmcnt(4)
    // drains tile 0 completely, leaves Alo1,Blo1 in flight (steady invariant).
    STAGE(0, 0); STAGE(0, 2); STAGE(0, 1); STAGE(0, 3);
    STAGE(1, 0); STAGE(1, 2);
    asm volatile("s_waitcnt vmcnt(4)" ::: "memory");
    __builtin_amdgcn_s_barrier();

    int tt = 0;
    #pragma unroll 1
    for (int it = 0; it < (NT - 1) / 2; ++it, tt += 2) {
        TILE(0, tt)
        TILE(1, tt + 1)
    }
    TILE(0, NT - 1)

    // epilogue: D col = lane&15 (n), row = (lane>>4)*4 + reg (m)
    const int bb = m0 >> 12;
    const int ms = (m0 & 4095) + wm * 128 + kq * 4;
    #pragma unroll
    for (int j = 0; j < 4; ++j) {
        const int n = n0 + wn * 64 + j * 16 + lr;
        const float bv = bias[n];
        float* ob = out + (size_t)bb * 4194304 + (size_t)n * 4096 + ms;
        #pragma unroll
        for (int i = 0; i < 8; ++i) {
            f32x4 v = acc[i][j];
            float4 o = make_float4(fmaxf(v[0] + bv, 0.f), fmaxf(v[1] + bv, 0.f),
                                   fmaxf(v[2] + bv, 0.f), fmaxf(v[3] + bv, 0.f));
            *(float4*)(ob + i * 16) = o;
        }
    }
    #undef LDA
    #undef LDB
    #undef MM
    #undef TILE
}

// ---------- launch ----------
extern "C" void kernel_launch(void* const* d_in, const int* in_sizes, int n_in,
                              void* d_out, int out_size, void* d_ws, size_t ws_size,
                              hipStream_t stream)
{
    const float* x    = (const float*)d_in[0];
    const float* W    = (const float*)d_in[1];
    const float* bias = (const float*)d_in[2];
    float* out        = (float*)d_out;

    char* ws = (char*)d_ws;
    // ws: xT 71,303,168 B ; Wb 2,228,224 B (total 73.5MB); fpart (52.4MB) in d_out
    // scratch (kgemm overwrites all of d_out afterwards -> deterministic replays).
    unsigned short* xT = (unsigned short*)ws;
    unsigned short* Wb = (unsigned short*)(ws + 71303168);
    float* fpart       = (float*)d_out;

    kWb_conv<<<1024, 256, 0, stream>>>(W, Wb);
    kT_conv <<<4096, 256, 0, stream>>>(x, xT);
    k1a_corr<<<512,  256, 0, stream>>>(x, fpart);
    k1b_norm<<<128,  256, 0, stream>>>(fpart, xT);
    kgemm   <<<512,  512, 0, stream>>>(xT, Wb, bias, out);
}

// Round 13
// 189.075 us; speedup vs baseline: 1.3799x; 1.0863x over previous
//
#include <hip/hip_runtime.h>

// ---------- types ----------
typedef __attribute__((ext_vector_type(8))) short bf16x8;   // 8 bf16 (4 VGPRs)
typedef __attribute__((ext_vector_type(4))) float f32x4;

__device__ __forceinline__ unsigned short f2bf(float f) {
    unsigned int u = __float_as_uint(f);
    unsigned int r = (u + 0x7fffu + ((u >> 16) & 1u)) >> 16;   // RNE
    return (unsigned short)r;
}

// x: (8,1024,64,64) f32; W: (1024,1049) f32; b: (1024,); out: (8,1024,64,64) f32
// M = 32768, K = 1049 -> pad 1088 (17 K-tiles of 64), N = 1024
#define KPAD 1088
#define NT   17

// ---------- fused front-end: k1a (blocks 0..1023) | kT (1024..5119) | kWb (5120..6143)
// Round-9 config (measured best: 192.4us) with the k1a branch REDESIGNED to fit the
// ~88-VGPR budget the co-compiled kernel gets (rounds 9/10: acc[25][4]=100 regs
// spilled; launch_bounds couldn't raise the allocation — rule #19). P=2 px/thread:
// acc[25][2]=50 regs + staging ~30 => fits. LDS floor rises (~38us) but hides under
// kT's HBM phase; the ~45us spill stall disappears. float2 window reads are
// stride-2 => 2 lanes/bank = free (m136).
__global__ __launch_bounds__(256, 2) void kfront(const float* __restrict__ x,
                                                 const float* __restrict__ W,
                                                 unsigned short* __restrict__ xT,
                                                 unsigned short* __restrict__ Wb,
                                                 float* __restrict__ fpart)
{
    __shared__ float4 lds_raw[1024];     // 16384 B, 16B-aligned union
    const int gbid = blockIdx.x;
    const int t    = threadIdx.x;

    if (gbid < 1024) {
        // ================= k1a: local self-correlation partials (P=2) =================
        // split(16) * b(8) * rowgroup(8: 8 rows). 256 thr: 8 rows x 32 strips x 2px.
        float (*slab)[12][68] = (float (*)[12][68])lds_raw;   // 6528 B
        const int split = gbid & 15;
        const int b     = (gbid >> 4) & 7;
        const int rg    = gbid >> 7;          // 0..7
        const int y0    = rg * 8;
        const int tc    = t & 31, tr = t >> 5;
        const int cs    = tc * 2;

        // zero halo cols (image cols -2,-1,64,65): 2 bufs x 12 rows x 4 cols = 96
        if (t < 96) {
            int buf = t / 48, rem = t % 48;
            int r = rem >> 2, cc = rem & 3;
            slab[buf][r][(cc < 2) ? cc : (64 + cc)] = 0.f;
        }

        float acc[25][2];
        #pragma unroll
        for (int s = 0; s < 25; ++s) { acc[s][0] = 0.f; acc[s][1] = 0.f; }

        const float* xb = x + ((size_t)b * 1024 + split * 64) * 4096;

        // staging: 12 rows x 16 float4-cols = 192 items, threads 0..191
        const int r0 = t >> 4, c40 = t & 15;
        const int y0r0 = y0 - 2 + r0;
        const bool has0 = (t < 192);

        #define K1A_LOAD(ch, VA)                                                     \
            if (has0) {                                                              \
                const float* s_ = xb + (size_t)(ch) * 4096;                          \
                VA = (y0r0 >= 0 && y0r0 < 64) ? *(const float4*)(s_ + y0r0 * 64 + c40 * 4) \
                                              : make_float4(0.f, 0.f, 0.f, 0.f);     \
            }
        #define K1A_WRITE(buf, VA)                                                   \
            if (has0) {                                                              \
                float2* d0 = (float2*)&slab[buf][r0][2 + c40 * 4];                   \
                d0[0] = make_float2(VA.x, VA.y);                                     \
                d0[1] = make_float2(VA.z, VA.w);                                     \
            }
        #define K1A_COMPUTE(buf)                                                     \
            {                                                                        \
                const float* base = &slab[buf][tr][cs];                              \
                float wf[6], ctr[2];                                                 \
                {                                                                    \
                    const float2* pr = (const float2*)(base + 2 * 68);               \
                    float2 w0 = pr[0], w1 = pr[1], w2 = pr[2];                       \
                    wf[0]=w0.x; wf[1]=w0.y; wf[2]=w1.x; wf[3]=w1.y;                  \
                    wf[4]=w2.x; wf[5]=w2.y;                                          \
                    ctr[0]=wf[2]; ctr[1]=wf[3];                                      \
                    _Pragma("unroll")                                                \
                    for (int dx = -2; dx <= 2; ++dx) {                               \
                        acc[12 + dx][0] += wf[2 + dx] * ctr[0];                      \
                        acc[12 + dx][1] += wf[3 + dx] * ctr[1];                      \
                    }                                                                \
                }                                                                    \
                _Pragma("unroll")                                                    \
                for (int r = 0; r < 5; ++r) {                                        \
                    if (r == 2) continue;                                            \
                    const float2* pr = (const float2*)(base + r * 68);               \
                    float2 w0 = pr[0], w1 = pr[1], w2 = pr[2];                       \
                    wf[0]=w0.x; wf[1]=w0.y; wf[2]=w1.x; wf[3]=w1.y;                  \
                    wf[4]=w2.x; wf[5]=w2.y;                                          \
                    _Pragma("unroll")                                                \
                    for (int dx = -2; dx <= 2; ++dx) {                               \
                        acc[r * 5 + dx + 2][0] += wf[2 + dx] * ctr[0];               \
                        acc[r * 5 + dx + 2][1] += wf[3 + dx] * ctr[1];               \
                    }                                                                \
                }                                                                    \
            }

        float4 Sa, Sb;
        K1A_LOAD(0, Sa)
        K1A_LOAD(1, Sb)
        K1A_WRITE(0, Sa)
        K1A_LOAD(2, Sa)
        __syncthreads();

        for (int i = 0; i < 64; i += 2) {
            K1A_WRITE(1, Sb)
            K1A_LOAD(min(i + 3, 63), Sb)
            K1A_COMPUTE(0)
            __syncthreads();
            K1A_WRITE(0, Sa)
            K1A_LOAD(min(i + 4, 63), Sa)
            K1A_COMPUTE(1)
            __syncthreads();
        }
        #undef K1A_LOAD
        #undef K1A_WRITE
        #undef K1A_COMPUTE

        const int mbase = b * 4096 + (y0 + tr) * 64 + cs;
        #pragma unroll
        for (int s = 0; s < 25; ++s) {
            *(float2*)(fpart + (size_t)(split * 25 + s) * 32768 + mbase) =
                make_float2(acc[s][0], acc[s][1]);
        }
    } else if (gbid < 5120) {
        // ================= kT: transpose+convert x -> xT[m][k] bf16 =================
        unsigned short (*tile)[128] = (unsigned short (*)[128])lds_raw;
        const int bid = gbid - 1024;         // 4096 = 512 mtiles * 8 ctiles
        const int mst = bid >> 3;
        const int ct  = bid & 7;
        const int m0  = mst * 64;
        const int b   = m0 >> 12, ms0 = m0 & 4095;
        const int msq = (t & 15) * 4;
        const int cg  = t >> 4;
        const int c0  = ct * 128 + cg * 8;

        const float* src = x + ((size_t)b * 1024 + c0) * 4096 + ms0 + msq;
        float4 v[8];
        #pragma unroll
        for (int j = 0; j < 8; ++j)
            v[j] = *(const float4*)(src + (size_t)j * 4096);

        #pragma unroll
        for (int p = 0; p < 4; ++p) {
            unsigned int w[4];
            #pragma unroll
            for (int q = 0; q < 4; ++q) {
                float lo = ((const float*)&v[2 * q])[p];
                float hi = ((const float*)&v[2 * q + 1])[p];
                w[q] = (unsigned int)f2bf(lo) | ((unsigned int)f2bf(hi) << 16);
            }
            const int row = msq + p;
            const int pch = cg ^ ((row >> 2) & 15);
            *(uint4*)&tile[row][pch * 8] = make_uint4(w[0], w[1], w[2], w[3]);
        }
        __syncthreads();

        #pragma unroll
        for (int q = 0; q < 4; ++q) {
            const int flat = q * 256 + t;
            const int row  = flat >> 4, ch = flat & 15;
            const int pch  = ch ^ ((row >> 2) & 15);
            uint4 val = *(const uint4*)&tile[row][pch * 8];
            *(uint4*)((char*)xT + (size_t)(m0 + row) * (KPAD * 2) + (size_t)(ct * 128 + ch * 8) * 2) = val;
        }
    } else {
        // ================= kWb: W f32 -> Wb[n][k] bf16, k padded =================
        const int o = gbid - 5120;           // 1024 blocks
        for (int k = t; k < KPAD; k += 256) {
            float v = (k < 1049) ? W[(size_t)o * 1049 + k] : 0.f;
            Wb[(size_t)o * KPAD + k] = f2bf(v);
        }
    }
}

// ---------- kernel: reduce 16 partials, L2-normalize, write bf16 into xT[m][1024..1088) ----------
__global__ void k1b_norm(const float* __restrict__ fpart, unsigned short* __restrict__ xT)
{
    const int m = blockIdx.x * 256 + threadIdx.x;
    float f[25];
    #pragma unroll
    for (int s = 0; s < 25; ++s) {
        float v = 0.f;
        #pragma unroll
        for (int sp = 0; sp < 16; ++sp)
            v += fpart[(size_t)(sp * 25 + s) * 32768 + m];
        f[s] = v;
    }
    float ss = 1e-6f;
    #pragma unroll
    for (int s = 0; s < 25; ++s) ss += f[s] * f[s];
    const float inv = 1.f / sqrtf(ss);

    unsigned int w[16];
    #pragma unroll
    for (int q = 0; q < 16; ++q) w[q] = 0u;
    #pragma unroll
    for (int s = 0; s < 25; ++s) {
        unsigned int h = f2bf(f[s] * inv);
        w[s >> 1] |= h << ((s & 1) * 16);
    }
    uint4* dst = (uint4*)((char*)xT + (size_t)m * (KPAD * 2) + 2048);
    dst[0] = make_uint4(w[0],  w[1],  w[2],  w[3]);
    dst[1] = make_uint4(w[4],  w[5],  w[6],  w[7]);
    dst[2] = make_uint4(w[8],  w[9],  w[10], w[11]);
    dst[3] = make_uint4(w[12], w[13], w[14], w[15]);
    uint4 z = make_uint4(0u, 0u, 0u, 0u);
    dst[4] = z; dst[5] = z; dst[6] = z; dst[7] = z;
}

// ---------- kernel: 256x256 8-phase GEMM, reads spread 12/4/8/0 across phases ----------
// (byte-identical to rounds 9-12)
__global__ __launch_bounds__(512, 2) void kgemm(const unsigned short* __restrict__ xT,
                                                const unsigned short* __restrict__ Wb,
                                                const float* __restrict__ bias,
                                                float* __restrict__ out)
{
    __shared__ unsigned short LA[2][256][64];   // 64KB
    __shared__ unsigned short LB[2][256][64];   // 64KB

    const int bid = blockIdx.x;                 // 512 blocks
    const int wg  = (bid & 7) * 64 + (bid >> 3);
    const int mt  = wg >> 2, nt = wg & 3;
    const int m0  = mt * 256, n0 = nt * 256;
    const int t   = threadIdx.x;
    const int l   = t & 63, w = t >> 6;
    const int lr  = l & 15, kq = l >> 4;
    const int wm  = w >> 2, wn = w & 3;

    const int sr = l >> 3;
    const int sp = (l & 7) ^ sr;
    const unsigned short* gA = xT + (size_t)(m0 + w * 8 + sr) * KPAD + sp * 8;
    const unsigned short* gB = Wb + (size_t)(n0 + w * 8 + sr) * KPAD + sp * 8;

    // half: 0 = A rows[0:128), 1 = A[128:256), 2 = B[0:128), 3 = B[128:256)
    auto STAGE = [&](int tt, int half) {
        if ((unsigned)tt >= NT) return;
        const int db = tt & 1;
        const size_t ko = (size_t)tt * 64;
        if (half < 2) {
            const unsigned short* g = gA + (size_t)(half * 128) * KPAD + ko;
            __builtin_amdgcn_global_load_lds((const void*)g,
                (void*)&LA[db][half * 128 + w * 8][0], 16, 0, 0);
            __builtin_amdgcn_global_load_lds((const void*)(g + (size_t)64 * KPAD),
                (void*)&LA[db][half * 128 + 64 + w * 8][0], 16, 0, 0);
        } else {
            const int hb = half - 2;
            const unsigned short* g = gB + (size_t)(hb * 128) * KPAD + ko;
            __builtin_amdgcn_global_load_lds((const void*)g,
                (void*)&LB[db][hb * 128 + w * 8][0], 16, 0, 0);
            __builtin_amdgcn_global_load_lds((const void*)(g + (size_t)64 * KPAD),
                (void*)&LB[db][hb * 128 + 64 + w * 8][0], 16, 0, 0);
        }
    };

    f32x4 zero = {0.f, 0.f, 0.f, 0.f};
    f32x4 acc[8][4];
    #pragma unroll
    for (int i = 0; i < 8; ++i)
        #pragma unroll
        for (int j = 0; j < 4; ++j) acc[i][j] = zero;

    bf16x8 a0[4][2], a1[4][2], b0[2][2], b1[2][2];

    #define LDA(dst, DB, ih)                                                     \
        _Pragma("unroll")                                                        \
        for (int i = 0; i < 4; ++i) {                                            \
            _Pragma("unroll")                                                    \
            for (int ks = 0; ks < 2; ++ks) {                                     \
                const int row = wm * 128 + ((ih) * 4 + i) * 16 + lr;             \
                const int slot = (ks * 4 + kq) ^ (row & 7);                      \
                dst[i][ks] = *(const bf16x8*)&LA[DB][row][slot * 8];             \
            }                                                                    \
        }
    #define LDB(dst, DB, jh)                                                     \
        _Pragma("unroll")                                                        \
        for (int j = 0; j < 2; ++j) {                                            \
            _Pragma("unroll")                                                    \
            for (int ks = 0; ks < 2; ++ks) {                                     \
                const int row = wn * 64 + ((jh) * 2 + j) * 16 + lr;              \
                const int slot = (ks * 4 + kq) ^ (row & 7);                      \
                dst[j][ks] = *(const bf16x8*)&LB[DB][row][slot * 8];             \
            }                                                                    \
        }
    #define MM(A, B, i0, j0)                                                     \
        _Pragma("unroll")                                                        \
        for (int ks = 0; ks < 2; ++ks) {                                         \
            _Pragma("unroll")                                                    \
            for (int i = 0; i < 4; ++i) {                                        \
                _Pragma("unroll")                                                \
                for (int j = 0; j < 2; ++j)                                      \
                    acc[(i0) + i][(j0) + j] = __builtin_amdgcn_mfma_f32_16x16x32_bf16( \
                        A[i][ks], B[j][ks], acc[(i0) + i][(j0) + j], 0, 0, 0);   \
            }                                                                    \
        }

    #define TILE(DB, TT)                                                         \
    {                                                                            \
        const int tti = (TT);                                                    \
        /* ph1: read a0(8)+b0(4); stage A-hi(t+1); MM(a0,b0) */                  \
        LDA(a0, DB, 0)                                                           \
        LDB(b0, DB, 0)                                                           \
        STAGE(tti + 1, 1);                                                       \
        asm volatile("s_waitcnt lgkmcnt(8)" ::: "memory");                       \
        __builtin_amdgcn_s_barrier();                                            \
        asm volatile("s_waitcnt lgkmcnt(0)" ::: "memory");                       \
        __builtin_amdgcn_sched_barrier(0);                                       \
        __builtin_amdgcn_s_setprio(1);                                           \
        MM(a0, b0, 0, 0)                                                         \
        __builtin_amdgcn_s_setprio(0);                                           \
        __builtin_amdgcn_s_barrier();                                            \
        /* ph2: read b1(4); stage B-hi(t+1); MM(a0,b1) */                        \
        LDB(b1, DB, 1)                                                           \
        STAGE(tti + 1, 3);                                                       \
        __builtin_amdgcn_s_barrier();                                            \
        asm volatile("s_waitcnt lgkmcnt(0)" ::: "memory");                       \
        __builtin_amdgcn_sched_barrier(0);                                       \
        __builtin_amdgcn_s_setprio(1);                                           \
        MM(a0, b1, 0, 2)                                                         \
        __builtin_amdgcn_s_setprio(0);                                           \
        __builtin_amdgcn_s_barrier();                                            \
        /* ph3: read a1(8); stage A-lo(t+2) [A-lo last read ph1]; MM(a1,b1) */   \
        LDA(a1, DB, 1)                                                           \
        STAGE(tti + 2, 0);                                                       \
        __builtin_amdgcn_s_barrier();                                            \
        asm volatile("s_waitcnt lgkmcnt(0)" ::: "memory");                       \
        __builtin_amdgcn_sched_barrier(0);                                       \
        __builtin_amdgcn_s_setprio(1);                                           \
        MM(a1, b1, 4, 2)                                                         \
        __builtin_amdgcn_s_setprio(0);                                           \
        __builtin_amdgcn_s_barrier();                                            \
        /* ph4: stage B-lo(t+2) [B-lo last read ph1]; MM(a1,b0); drain t+1 */    \
        STAGE(tti + 2, 2);                                                       \
        __builtin_amdgcn_s_barrier();                                            \
        __builtin_amdgcn_s_setprio(1);                                           \
        MM(a1, b0, 4, 0)                                                         \
        __builtin_amdgcn_s_setprio(0);                                           \
        if (tti + 2 < NT) {                                                      \
            asm volatile("s_waitcnt vmcnt(4)" ::: "memory");                     \
        } else {                                                                 \
            asm volatile("s_waitcnt vmcnt(0)" ::: "memory");                     \
        }                                                                        \
        __builtin_amdgcn_s_barrier();                                            \
    }

    // prologue FIFO: Alo0,Blo0,Ahi0,Bhi0,Alo1,Blo1 (12 loads); vmcnt(4)
    // drains tile 0 completely, leaves Alo1,Blo1 in flight (steady invariant).
    STAGE(0, 0); STAGE(0, 2); STAGE(0, 1); STAGE(0, 3);
    STAGE(1, 0); STAGE(1, 2);
    asm volatile("s_waitcnt vmcnt(4)" ::: "memory");
    __builtin_amdgcn_s_barrier();

    int tt = 0;
    #pragma unroll 1
    for (int it = 0; it < (NT - 1) / 2; ++it, tt += 2) {
        TILE(0, tt)
        TILE(1, tt + 1)
    }
    TILE(0, NT - 1)

    // epilogue: D col = lane&15 (n), row = (lane>>4)*4 + reg (m)
    const int bb = m0 >> 12;
    const int ms = (m0 & 4095) + wm * 128 + kq * 4;
    #pragma unroll
    for (int j = 0; j < 4; ++j) {
        const int n = n0 + wn * 64 + j * 16 + lr;
        const float bv = bias[n];
        float* ob = out + (size_t)bb * 4194304 + (size_t)n * 4096 + ms;
        #pragma unroll
        for (int i = 0; i < 8; ++i) {
            f32x4 v = acc[i][j];
            float4 o = make_float4(fmaxf(v[0] + bv, 0.f), fmaxf(v[1] + bv, 0.f),
                                   fmaxf(v[2] + bv, 0.f), fmaxf(v[3] + bv, 0.f));
            *(float4*)(ob + i * 16) = o;
        }
    }
    #undef LDA
    #undef LDB
    #undef MM
    #undef TILE
}

// ---------- launch ----------
extern "C" void kernel_launch(void* const* d_in, const int* in_sizes, int n_in,
                              void* d_out, int out_size, void* d_ws, size_t ws_size,
                              hipStream_t stream)
{
    const float* x    = (const float*)d_in[0];
    const float* W    = (const float*)d_in[1];
    const float* bias = (const float*)d_in[2];
    float* out        = (float*)d_out;

    char* ws = (char*)d_ws;
    // ws: xT 71,303,168 B ; Wb 2,228,224 B (total 73.5MB); fpart (52.4MB) in d_out
    // scratch (kgemm overwrites all of d_out afterwards -> deterministic replays).
    unsigned short* xT = (unsigned short*)ws;
    unsigned short* Wb = (unsigned short*)(ws + 71303168);
    float* fpart       = (float*)d_out;

    kfront <<<6144, 256, 0, stream>>>(x, W, xT, Wb, fpart);
    k1b_norm<<<128,  256, 0, stream>>>(fpart, xT);
    kgemm  <<<512,  512, 0, stream>>>(xT, Wb, bias, out);
}